// Round 8
// baseline (170.361 us; speedup 1.0000x reference)
//
#include <hip/hip_runtime.h>
#include <hip/hip_bf16.h>

// Problem constants
#define B_    4
#define T_    4096
#define C_    512
#define H_    8
#define D_    64
#define KS_   9
#define PAD_  4
#define MTOT  (B_ * T_)          // 16384
#define PLANE (MTOT * C_)        // elements per q/k/v plane
#define WU    (C_ * C_ / 8)      // weight units of 8 elements

typedef __bf16 bf16_t;
typedef __bf16 bf16x8 __attribute__((ext_vector_type(8)));
typedef float  f32x4  __attribute__((ext_vector_type(4)));
typedef unsigned int  uint2v __attribute__((ext_vector_type(2)));

// ---------------------------------------------------------------------------
// fp32 -> bf16 for the 4 weight matrices AND x (GEMM A consumed via
// global_load_lds which cannot convert). 4*WU + PLANE/8 units, 8 elem each.
// ---------------------------------------------------------------------------
__global__ __launch_bounds__(256)
void conv_all(const float* __restrict__ Wq, const float* __restrict__ Wk,
              const float* __restrict__ Wv, const float* __restrict__ Wo,
              const float* __restrict__ x,
              bf16_t* __restrict__ Wb, bf16_t* __restrict__ xb) {
  int i = blockIdx.x * 256 + threadIdx.x;
  const float* src;
  bf16_t* dst;
  if (i < 4 * WU) {                        // WU = 1<<15
    int w = i >> 15;
    const float* W = (w == 0) ? Wq : (w == 1) ? Wk : (w == 2) ? Wv : Wo;
    src = W + (size_t)(i & (WU - 1)) * 8;
    dst = Wb + (size_t)i * 8;
  } else {
    size_t j = (size_t)(i - 4 * WU);
    src = x + j * 8;
    dst = xb + j * 8;
  }
  float4 f0 = ((const float4*)src)[0];
  float4 f1 = ((const float4*)src)[1];
  bf16x8 o;
  o[0] = (bf16_t)f0.x; o[1] = (bf16_t)f0.y; o[2] = (bf16_t)f0.z; o[3] = (bf16_t)f0.w;
  o[4] = (bf16_t)f1.x; o[5] = (bf16_t)f1.y; o[6] = (bf16_t)f1.z; o[7] = (bf16_t)f1.w;
  *(bf16x8*)dst = o;
}

// ---------------------------------------------------------------------------
// GEMM round 8 = r7 (best, 166.07) + TRANSPOSED-OUTPUT EPILOGUE.
// r7 loop kept byte-identical: BM=128 BN=128 BK=32, ring-3 of 16KB slots
// (48KB LDS, 3 blocks/CU), 4 waves 2mx2n, XOR chunk swizzle, compiler-
// scheduled lgkmcnt (no pins), counted vmcnt(4) boundary, 1 barrier/tile,
// setprio around the MFMA cluster.
// r8 change: epilogue store-issue was never examined -- MODE0 did 64 scalar
// 2-byte stores/thread at 128B stride (~24.6k issue-cyc/SIMD ~ 10us inside
// gemm0) because the m89 C/D layout gives a lane 4 consecutive T values at
// fixed d (wrong axis for [t][d] planes). The 16x16x32 A/B operand layouts
// are symmetric (lane = free-dim row, 8 k-contiguous elems), so SWAPPING
// the operands -- mfma(bfr, af) -- computes the same sums with D transposed:
//   col(lane&15) = t_local, row((lane>>4)*4+reg) = n_local.
// A lane now holds 4 CONSECUTIVE n/d values at fixed t: MODE0 packs them
// into one 8B store (bf16x4), MODE1 into one float4 -- 16 stores/thread
// instead of 64. Math/accumulation order bit-identical.
// MODE 0: A = xb bf16 [MTOT][C], Bw = Wq|Wk|Wv packed, out -> qkv planes.
// MODE 1: A = y bf16 per-head planes (K-tile kt -> head kt>>1), out fp32.
// ---------------------------------------------------------------------------
#define BM   128
#define BN   128
#define BK   32
#define NKT  (C_ / BK)            // 16
#define ASL  (BM * BK)            // 4096 elems per A slot (8KB)
#define SLOT (2 * ASL)            // A + B = 8192 elems (16KB)

#define GLD(srcp, off) __builtin_amdgcn_global_load_lds(                     \
    (const __attribute__((address_space(1))) unsigned int*)(srcp),           \
    (__attribute__((address_space(3))) unsigned int*)(&sm[off]), 16, 0, 0)

template<int MODE>
__global__ __launch_bounds__(256, 3)
void gemm8p(const bf16_t* __restrict__ A, const bf16_t* __restrict__ Bw,
            const float* __restrict__ b0, const float* __restrict__ b1,
            const float* __restrict__ b2, void* __restrict__ Outp) {
  __shared__ __align__(16) bf16_t sm[3 * SLOT];   // 48 KB

  constexpr int GX  = (MODE == 0) ? (3 * C_ / BN) : (C_ / BN);  // 12 / 4
  constexpr int NWG = GX * (MTOT / BM);                         // 1536 / 512
  constexpr int CPX = NWG / 8;                                  // NWG%8==0

  // XCD swizzle (m157): each XCD owns contiguous logical tiles (complete
  // m-panels), so an A panel's n-tiles share one L2.
  const int ord = blockIdx.y * GX + blockIdx.x;
  const int lg  = (ord & 7) * CPX + (ord >> 3);
  const int n0  = (lg % GX) * BN;
  const int m0  = (lg / GX) * BM;

  const int tid  = threadIdx.x;
  const int lane = tid & 63;
  const int wave = tid >> 6;
  const int wm   = wave >> 1;          // 0..1  (64-row slice)
  const int wn   = wave & 1;           // 0..1  (64-col slice)
  const int lr   = lane & 15;          // fragment row
  const int lq   = lane >> 4;          // k-chunk of the fragment

  // Staging sources (inverse-swizzled global addresses).
  // A: 512 16B units (2/thread); B: 512 units (2/thread).
  const bf16_t* aSrc[2];
  const bf16_t* bSrc[2];
#pragma unroll
  for (int s = 0; s < 2; ++s) {
    int u = s * 256 + tid, r = u >> 2, sl = u & 3;
    int cs = (sl ^ ((r >> 1) & 3)) << 3;
    if constexpr (MODE == 0) {
      aSrc[s] = A + (size_t)(m0 + r) * C_ + cs;
    } else {
      int bb = m0 >> 12, t0 = m0 & (T_ - 1);
      aSrc[s] = A + ((size_t)bb * H_ * T_ + t0 + r) * D_ + cs;  // head 0 base
    }
    bSrc[s] = Bw + (size_t)(n0 + r) * C_ + cs;
  }
  // K-tile element offset within the A source. MODE 1: head kt>>1, half kt&1.
  auto ofsA = [](int kt) -> size_t {
    if constexpr (MODE == 0) return (size_t)kt * BK;
    else return (size_t)(kt >> 1) * ((size_t)T_ * D_) + (size_t)(kt & 1) * 32;
  };

  // Prologue: kt0 -> slot0, kt1 -> slot1; wait kt0 only (kt1's 4 in flight).
#pragma unroll
  for (int s = 0; s < 2; ++s) GLD(aSrc[s] + ofsA(0), (s * 256 + tid) * 8);
#pragma unroll
  for (int s = 0; s < 2; ++s) GLD(bSrc[s], ASL + (s * 256 + tid) * 8);
#pragma unroll
  for (int s = 0; s < 2; ++s) GLD(aSrc[s] + ofsA(1), SLOT + (s * 256 + tid) * 8);
#pragma unroll
  for (int s = 0; s < 2; ++s) GLD(bSrc[s] + BK, SLOT + ASL + (s * 256 + tid) * 8);
  asm volatile("s_waitcnt vmcnt(4)" ::: "memory");
  __builtin_amdgcn_s_barrier();

  f32x4 acc[4][4] = {};
  const int co = ((lq ^ ((lr >> 1) & 3)) << 3);   // swizzled chunk offset

#pragma unroll
  for (int kt = 0; kt < NKT; ++kt) {
    const int rsl = kt % 3;
    const int wof = ((kt + 2) % 3) * SLOT;
    const bf16_t* abase = &sm[rsl * SLOT + (wm * 64 + lr) * BK + co];
    const bf16_t* bbase = &sm[rsl * SLOT + ASL + (wn * 64 + lr) * BK + co];

    // ds_read the 8 fragments; slot rsl full since boundary kt-1.
    bf16x8 af[4], bfr[4];
#pragma unroll
    for (int i = 0; i < 4; ++i) {
      af[i]  = *(const bf16x8*)(abase + i * (16 * BK));
      bfr[i] = *(const bf16x8*)(bbase + i * (16 * BK));
    }
    // Stage kt+2 -> slot (kt+2)%3 (readers finished before boundary kt-1).
    if (kt + 2 < NKT) {
#pragma unroll
      for (int s = 0; s < 2; ++s)
        GLD(aSrc[s] + ofsA(kt + 2), wof + (s * 256 + tid) * 8);
#pragma unroll
      for (int s = 0; s < 2; ++s)
        GLD(bSrc[s] + (size_t)(kt + 2) * BK, wof + ASL + (s * 256 + tid) * 8);
    }
    // Compiler-scheduled lgkmcnt (r7): progressive waits, interleaved issue.
    __builtin_amdgcn_s_setprio(1);
#pragma unroll
    for (int i = 0; i < 4; ++i)
#pragma unroll
      for (int j = 0; j < 4; ++j)
        acc[i][j] = __builtin_amdgcn_mfma_f32_16x16x32_bf16(
            bfr[j], af[i], acc[i][j], 0, 0, 0);   // SWAPPED: D[n][t]
    __builtin_amdgcn_s_setprio(0);
    // Boundary: counted vmcnt (T4) -- kt+1's 4 loads landed, kt+2's 4 stay
    // in flight. vmcnt(0) only at the last staged boundary.
    if (kt + 2 < NKT)       asm volatile("s_waitcnt vmcnt(4)" ::: "memory");
    else if (kt + 2 == NKT) asm volatile("s_waitcnt vmcnt(0)" ::: "memory");
    if (kt + 1 < NKT) __builtin_amdgcn_s_barrier();
  }

  // Epilogue, transposed D: col(lane&15) = t_local, regs = 4 consecutive n.
  const int tl = lane & 15;
  const int dq = (lane >> 4) << 2;
  if constexpr (MODE == 0) {
    const int z  = n0 >> 9;                        // BN=128 | 512 -> z uniform
    const float* bias = (z == 0) ? b0 : (z == 1) ? b1 : b2;
    const int bb = m0 >> 12;
    const int t0 = m0 & (T_ - 1);
    bf16_t* plane = (bf16_t*)Outp + (size_t)z * PLANE;
#pragma unroll
    for (int j = 0; j < 4; ++j) {
      const int cc = (n0 & (C_ - 1)) + wn * 64 + j * 16 + dq;  // 4-aligned
      const int hh = cc >> 6, dd = cc & 63;        // quad never crosses head
      const float4 bq4 = *(const float4*)(bias + cc);
      bf16_t* hb = plane + ((size_t)(bb * H_ + hh) * T_) * D_ + dd;
#pragma unroll
      for (int i = 0; i < 4; ++i) {
        const int t = t0 + wm * 64 + i * 16 + tl;
        bf16_t v0 = (bf16_t)(acc[i][j][0] + bq4.x);
        bf16_t v1 = (bf16_t)(acc[i][j][1] + bq4.y);
        bf16_t v2 = (bf16_t)(acc[i][j][2] + bq4.z);
        bf16_t v3 = (bf16_t)(acc[i][j][3] + bq4.w);
        unsigned int lo = ((unsigned short*)&v0)[0] |
                          ((unsigned int)((unsigned short*)&v1)[0] << 16);
        unsigned int hi = ((unsigned short*)&v2)[0] |
                          ((unsigned int)((unsigned short*)&v3)[0] << 16);
        uint2v pk; pk[0] = lo; pk[1] = hi;
        *(uint2v*)(hb + (size_t)t * D_) = pk;      // one 8B store
      }
    }
  } else {
    float* outp = (float*)Outp;
#pragma unroll
    for (int j = 0; j < 4; ++j) {
      const int n = n0 + wn * 64 + j * 16 + dq;    // 4-aligned -> 16B aligned
      const float4 bq4 = *(const float4*)(b0 + n);
#pragma unroll
      for (int i = 0; i < 4; ++i) {
        const int m = m0 + wm * 64 + i * 16 + tl;
        float4 v;
        v.x = acc[i][j][0] + bq4.x;
        v.y = acc[i][j][1] + bq4.y;
        v.z = acc[i][j][2] + bq4.z;
        v.w = acc[i][j][3] + bq4.w;
        *(float4*)(outp + (size_t)m * C_ + n) = v; // one 16B store
      }
    }
  }
}

// ---------------------------------------------------------------------------
// Neighborhood attention: 8 threads per (b,h,t), d-octet each; width-8
// shfl_xor score reduce; per-head plane I/O (fully coalesced). Unchanged.
// ---------------------------------------------------------------------------
__global__ __launch_bounds__(256)
void attn_kernel(const bf16_t* __restrict__ qkv, bf16_t* __restrict__ y) {
  const int tid  = threadIdx.x;
  const int sub  = tid & 7;
  const int tl   = tid >> 3;
  const int t    = blockIdx.x * 32 + tl;
  const int h    = blockIdx.y;
  const int b    = blockIdx.z;

  const size_t pl = (size_t)(b * H_ + h) * T_ * D_;
  const bf16_t* q = qkv + pl;
  const bf16_t* k = qkv + (size_t)PLANE + pl;
  const bf16_t* v = qkv + (size_t)2 * PLANE + pl;
  const int c = sub * 8;

  int tj[KS_];
#pragma unroll
  for (int j = 0; j < KS_; ++j) {
    int tt = t - PAD_ + j;
    tj[j] = tt < 0 ? 0 : (tt >= T_ ? T_ - 1 : tt);
  }

  bf16x8 q8 = *(const bf16x8*)(q + (size_t)t * D_ + c);
  float qf[8];
#pragma unroll
  for (int e = 0; e < 8; ++e) qf[e] = (float)q8[e];

  float s[KS_];
#pragma unroll
  for (int j = 0; j < KS_; ++j) {
    bf16x8 k8 = *(const bf16x8*)(k + (size_t)tj[j] * D_ + c);
    float d0 = 0.f;
#pragma unroll
    for (int e = 0; e < 8; ++e) d0 += qf[e] * (float)k8[e];
    s[j] = d0;
  }

#pragma unroll
  for (int m = 1; m < 8; m <<= 1)
#pragma unroll
    for (int j = 0; j < KS_; ++j) s[j] += __shfl_xor(s[j], m, 8);

  float mx = s[0];
#pragma unroll
  for (int j = 1; j < KS_; ++j) mx = fmaxf(mx, s[j]);
  float w[KS_], sum = 0.f;
#pragma unroll
  for (int j = 0; j < KS_; ++j) {
    w[j] = __expf((s[j] - mx) * 0.125f);   // scale = 1/sqrt(64)
    sum += w[j];
  }
  const float inv = 1.f / sum;
#pragma unroll
  for (int j = 0; j < KS_; ++j) w[j] *= inv;

  float o[8] = {0.f, 0.f, 0.f, 0.f, 0.f, 0.f, 0.f, 0.f};
#pragma unroll
  for (int j = 0; j < KS_; ++j) {
    bf16x8 v8 = *(const bf16x8*)(v + (size_t)tj[j] * D_ + c);
#pragma unroll
    for (int e = 0; e < 8; ++e) o[e] += w[j] * (float)v8[e];
  }
  bf16x8 o8;
#pragma unroll
  for (int e = 0; e < 8; ++e) o8[e] = (bf16_t)o[e];
  *(bf16x8*)(y + pl + (size_t)t * D_ + c) = o8;
}

// ---------------------------------------------------------------------------
extern "C" void kernel_launch(void* const* d_in, const int* in_sizes, int n_in,
                              void* d_out, int out_size, void* d_ws, size_t ws_size,
                              hipStream_t stream) {
  const float* x  = (const float*)d_in[0];
  const float* Wq = (const float*)d_in[1];
  const float* bq = (const float*)d_in[2];
  const float* Wk = (const float*)d_in[3];
  const float* bk = (const float*)d_in[4];
  const float* Wv = (const float*)d_in[5];
  const float* bv = (const float*)d_in[6];
  const float* Wo = (const float*)d_in[7];
  const float* bo = (const float*)d_in[8];
  float* out = (float*)d_out;

  // Workspace: Wb 2MB | xb 16.8MB | qkv 50.3MB  (y aliases xb: xb is dead
  // once gemm8p<0> completes; attn writes y, gemm8p<1> reads it). ~69MB.
  bf16_t* Wb  = (bf16_t*)d_ws;
  bf16_t* xb  = Wb + (size_t)4 * C_ * C_;
  bf16_t* qkv = xb + (size_t)PLANE;
  bf16_t* y   = xb;

  conv_all<<<(4 * WU + PLANE / 8) / 256, 256, 0, stream>>>(Wq, Wk, Wv, Wo, x, Wb, xb);
  gemm8p<0><<<dim3(3 * C_ / BN, MTOT / BM), 256, 0, stream>>>(
      xb, Wb, bq, bk, bv, qkv);
  attn_kernel<<<dim3(T_ / 32, H_, B_), 256, 0, stream>>>(qkv, y);
  gemm8p<1><<<dim3(C_ / BN, MTOT / BM), 256, 0, stream>>>(
      y, Wb + (size_t)3 * C_ * C_, bo, nullptr, nullptr, out);
}